// Round 2
// baseline (352.159 us; speedup 1.0000x reference)
//
#include <hip/hip_runtime.h>
#include <math.h>
#include <stdint.h>

// RGWRP via histogram ranking (sort-free, int-atomics only).
//
// out[row] = sum_{r<905} sorted_desc(x_row)[r] * d^r / sum_{r<905} d^r,
// d = 0.01^(1/904).
//
// Approximation: quantize values to 2048 linear bins over the row's
// [min,max]; represent every value in a bin by the BIN CENTER. Counting-sort
// ranks are exact for quantized values; total output error <= ~1 bin width
// (~0.004 for N(0,1) rows) << 4.03e-2 threshold.
//
// R4 restructure vs R3 (256x16):
//  * 512 threads x 8 elems: live regs ~40 (v[8] + 4-count scan) so the
//    64-VGPR cap from __launch_bounds__(512,8) holds WITHOUT scratch spills
//    (theory: 256x16's v[16]+c[8]+p[8] overflowed the 64-reg budget ->
//    ~0.5-1 GB scratch traffic was the gap to the HBM roofline).
//  * telescoped decay weights: a thread's 4 bins are rank-adjacent, so
//    end_i == start_{i+1}; 5 exp2f/thread instead of up to 16, no per-bin
//    branch (empty bins give wr=0 automatically).
//  * scan counts loaded as one uint4 (ds_read_b128) instead of 8 strided
//    b32 reads (8-way bank conflict).
//
// Per row (block of 512 threads):
//  1. load 8 floats/thread (coalesced float4 x2)
//  2. block min/max reduce -> bin scale
//  3. LDS histogram: cnt[bin]++  (native ds_add_u32 only)
//  4. exclusive suffix-scan of cnt from top bin -> rank start per bin
//  5. bin contribution: center(b) * (d^start - d^end), clipped at rank 905
//  6. block reduce, scale by 1/(1-d^905)
//
// (R5 = R4 resubmitted verbatim: R4 bench failed with GPUAcquisitionTimeout,
//  no counters were produced.)

#define K_TOP    905
#define ROW_LEN  4096
#define THREADS  512
#define NREG     8                 // ROW_LEN / THREADS
#define BINS     2048
#define PER_T    (BINS / THREADS)  // 4 bins per thread
#define NWAVES   (THREADS / 64)    // 8

__global__ __launch_bounds__(THREADS, 8) void rgwrp_kernel(
    const float* __restrict__ x, float* __restrict__ out,
    float l2d /* log2(d) */, float scaleOut /* 1/(1-d^905) */) {
  const int tid  = threadIdx.x;
  const int lane = tid & 63;
  const int wave = tid >> 6;
  const int row  = blockIdx.x;

  __shared__ unsigned cnt[BINS];
  __shared__ float    redMn[NWAVES], redMx[NWAVES];
  __shared__ unsigned redCnt[NWAVES];
  __shared__ float    redC[NWAVES];

  // ---- clear histogram (stride-512: conflict-free) ----
#pragma unroll
  for (int i = 0; i < PER_T; ++i) cnt[tid + i * THREADS] = 0u;

  // ---- load 8 elements/thread ----
  float v[NREG];
  const float4* xr = (const float4*)(x + (size_t)row * ROW_LEN);
#pragma unroll
  for (int i = 0; i < NREG / 4; ++i) {
    float4 t = xr[i * THREADS + tid];
    v[4 * i + 0] = t.x; v[4 * i + 1] = t.y;
    v[4 * i + 2] = t.z; v[4 * i + 3] = t.w;
  }

  // ---- block min/max ----
  float vmn = v[0], vmx = v[0];
#pragma unroll
  for (int i = 1; i < NREG; ++i) {
    vmn = fminf(vmn, v[i]);
    vmx = fmaxf(vmx, v[i]);
  }
#pragma unroll
  for (int off = 32; off > 0; off >>= 1) {
    vmn = fminf(vmn, __shfl_down(vmn, off));
    vmx = fmaxf(vmx, __shfl_down(vmx, off));
  }
  if (lane == 0) { redMn[wave] = vmn; redMx[wave] = vmx; }
  __syncthreads();  // covers clears + redMn/redMx writes
  vmn = redMn[0]; vmx = redMx[0];
#pragma unroll
  for (int w = 1; w < NWAVES; ++w) {
    vmn = fminf(vmn, redMn[w]);
    vmx = fmaxf(vmx, redMx[w]);
  }

  const float range    = fmaxf(vmx - vmn, 1e-20f);
  const float scale    = (float)BINS / range;
  const float invScale = range * (1.0f / (float)BINS);

  // ---- histogram: counts only (native ds_add_u32) ----
  // b >= 0 guaranteed (v >= vmn); only upper clamp needed.
#pragma unroll
  for (int i = 0; i < NREG; ++i) {
    int b = (int)((v[i] - vmn) * scale);
    b = b > BINS - 1 ? BINS - 1 : b;
    atomicAdd(&cnt[b], 1u);
  }
  __syncthreads();

  // ---- exclusive suffix-scan of counts in DESCENDING bin order ----
  // thread t owns descending positions j in [t*4, t*4+4), bin = 2047 - j.
  // One aligned uint4 read covers words [2044-jbase .. 2047-jbase].
  const int jbase = tid * PER_T;
  const uint4 q = *(const uint4*)&cnt[BINS - PER_T - jbase];
  const unsigned c0 = q.w, c1 = q.z, c2 = q.y, c3 = q.x;  // descending order
  const unsigned p1 = c0, p2 = c0 + c1, p3 = c0 + c1 + c2;
  const unsigned run = p3 + c3;

  // wave-level inclusive scan of per-thread totals
  unsigned incl = run;
#pragma unroll
  for (int off = 1; off < 64; off <<= 1) {
    unsigned t = __shfl_up(incl, off);
    if (lane >= off) incl += t;
  }
  const unsigned laneEx = incl - run;
  if (lane == 63) redCnt[wave] = incl;  // wave total
  __syncthreads();
  unsigned waveEx = 0;
#pragma unroll
  for (int w = 0; w < NWAVES - 1; ++w)
    if (w < wave) waveEx += redCnt[w];
  const unsigned base = waveEx + laneEx;

  // ---- per-bin contribution, telescoped ----
  // Ranks are adjacent across a thread's 4 bins: end_i == start_{i+1}.
  // With g(r) = d^min(r,905): wr_i = g(r_i) - g(r_{i+1}); empty bins and
  // fully-below-cutoff bins give wr = 0 automatically.
  float contrib = 0.f;
  if (base < (unsigned)K_TOP && run) {
    const unsigned kt = (unsigned)K_TOP;
    const unsigned r1 = min(base + p1, kt);
    const unsigned r2 = min(base + p2, kt);
    const unsigned r3 = min(base + p3, kt);
    const unsigned r4 = min(base + run, kt);
    const float e0 = exp2f((float)base * l2d);
    const float e1 = exp2f((float)r1 * l2d);
    const float e2 = exp2f((float)r2 * l2d);
    const float e3 = exp2f((float)r3 * l2d);
    const float e4 = exp2f((float)r4 * l2d);
    const float cb = vmn + ((float)(BINS - 1 - jbase) + 0.5f) * invScale;
    contrib = (e0 - e1) * cb
            + (e1 - e2) * (cb - invScale)
            + (e2 - e3) * (cb - 2.f * invScale)
            + (e3 - e4) * (cb - 3.f * invScale);
  }

  // ---- block reduce ----
#pragma unroll
  for (int off = 32; off > 0; off >>= 1)
    contrib += __shfl_down(contrib, off);
  if (lane == 0) redC[wave] = contrib;
  __syncthreads();
  if (tid == 0) {
    float s = redC[0];
#pragma unroll
    for (int w = 1; w < NWAVES; ++w) s += redC[w];
    out[row] = s * scaleOut;
  }
}

extern "C" void kernel_launch(void* const* d_in, const int* in_sizes, int n_in,
                              void* d_out, int out_size, void* d_ws, size_t ws_size,
                              hipStream_t stream) {
  (void)in_sizes; (void)n_in; (void)d_ws; (void)ws_size; (void)out_size;
  const float* x = (const float*)d_in[0];
  float* out = (float*)d_out;

  const double d = pow(0.01, 1.0 / 904.0);
  const float l2d = (float)(log2(d));                       // log2 of decay
  const float scaleOut = (float)(1.0 / (1.0 - pow(0.01, 905.0 / 904.0)));

  rgwrp_kernel<<<16384, THREADS, 0, stream>>>(x, out, l2d, scaleOut);
}